// Round 2
// baseline (5815.086 us; speedup 1.0000x reference)
//
#include <hip/hip_runtime.h>
#include <hip/hip_cooperative_groups.h>
#include <stdint.h>

// SEQ=256, B=64, DIM=1024, UNITS=1024, 4U=4096
typedef unsigned short ushort_t;
typedef __attribute__((ext_vector_type(8))) short s16x8;
typedef __attribute__((ext_vector_type(4))) float f32x4;
typedef __attribute__((ext_vector_type(4))) unsigned short u16x4;

#define TO_GLB(p) ((const __attribute__((address_space(1))) void*)(p))
#define TO_LDS(p) ((__attribute__((address_space(3))) void*)(p))

__device__ __forceinline__ ushort_t f2bf(float f) {
  union { float f; uint32_t u; } v; v.f = f;
  uint32_t u = v.u;
  uint32_t r = (u + 0x7FFFu + ((u >> 16) & 1u)) >> 16;
  return (ushort_t)r;
}
__device__ __forceinline__ float bf2f(ushort_t b) {
  union { uint32_t u; float f; } v; v.u = ((uint32_t)b) << 16;
  return v.f;
}
__device__ __forceinline__ float sigm(float x) {
  x = fminf(fmaxf(x, -30.f), 30.f);
  return 1.0f / (1.0f + __expf(-x));
}
__device__ __forceinline__ float tanh_f(float x) {
  x = fminf(fmaxf(x, -15.f), 15.f);
  float t = __expf(2.0f * x);
  return (t - 1.0f) / (t + 1.0f);
}

// ---------------- convert f32 -> bf16, 4 elems/thread ----------------
__global__ void conv_f32_to_bf16(const float* __restrict__ src,
                                 ushort_t* __restrict__ dst, int n4) {
  int i = blockIdx.x * blockDim.x + threadIdx.x;
  if (i < n4) {
    float4 v = ((const float4*)src)[i];
    u16x4 o;
    o[0] = f2bf(v.x); o[1] = f2bf(v.y); o[2] = f2bf(v.z); o[3] = f2bf(v.w);
    *(u16x4*)(dst + 4 * (size_t)i) = o;
  }
}

// ---------------- init h0 (bf16) from hx ----------------
__global__ void init_h(const float* __restrict__ hx, ushort_t* __restrict__ h0, int n) {
  int i = blockIdx.x * blockDim.x + threadIdx.x;
  if (i < n) h0[i] = f2bf(hx[i]);
}

// ---------------- x_proj GEMM: C[16384][4096] = A @ W_ih^T + b_ih + b_hh ----
__global__ __launch_bounds__(256) void gemm_xproj(
    const ushort_t* __restrict__ A,   // x bf16 [16384][1024]
    const ushort_t* __restrict__ Bw,  // W_ih bf16 [4096][1024]
    const float* __restrict__ b_ih, const float* __restrict__ b_hh,
    ushort_t* __restrict__ C)         // x_proj bf16 [16384][4096]
{
  __shared__ ushort_t As[128 * 32];
  __shared__ ushort_t Bs[128 * 32];
  const int t = threadIdx.x;
  const int lane = t & 63;
  const int wid = t >> 6;
  const int wr = wid >> 1, wc = wid & 1;
  const size_t tm = (size_t)blockIdx.x * 128;
  const size_t tn = (size_t)blockIdx.y * 128;

  f32x4 acc[4][4];
  const f32x4 zero = {0.f, 0.f, 0.f, 0.f};
#pragma unroll
  for (int m = 0; m < 4; m++)
#pragma unroll
    for (int n = 0; n < 4; n++) acc[m][n] = zero;

  for (int k0 = 0; k0 < 1024; k0 += 32) {
    __syncthreads();
#pragma unroll
    for (int i = 0; i < 2; i++) {
      int row = i * 64 + (t >> 2);
      int kc = (t & 3) * 8;
      const ushort_t* ga = A + (tm + row) * 1024 + k0 + kc;
      __builtin_amdgcn_global_load_lds(TO_GLB(ga),
          TO_LDS((char*)As + (i * 256 + wid * 64) * 16), 16, 0, 0);
      const ushort_t* gb = Bw + (tn + row) * 1024 + k0 + kc;
      __builtin_amdgcn_global_load_lds(TO_GLB(gb),
          TO_LDS((char*)Bs + (i * 256 + wid * 64) * 16), 16, 0, 0);
    }
    __syncthreads();
    s16x8 af[4], bfr[4];
#pragma unroll
    for (int m = 0; m < 4; m++) {
      int r = wr * 64 + m * 16 + (lane & 15);
      af[m] = *(const s16x8*)((const char*)As + r * 64 + (lane >> 4) * 16);
    }
#pragma unroll
    for (int n = 0; n < 4; n++) {
      int r = wc * 64 + n * 16 + (lane & 15);
      bfr[n] = *(const s16x8*)((const char*)Bs + r * 64 + (lane >> 4) * 16);
    }
#pragma unroll
    for (int m = 0; m < 4; m++)
#pragma unroll
      for (int n = 0; n < 4; n++)
        acc[m][n] = __builtin_amdgcn_mfma_f32_16x16x32_bf16(af[m], bfr[n], acc[m][n], 0, 0, 0);
  }

#pragma unroll
  for (int m = 0; m < 4; m++)
#pragma unroll
    for (int n = 0; n < 4; n++)
#pragma unroll
      for (int j = 0; j < 4; j++) {
        size_t row = tm + wr * 64 + m * 16 + ((lane >> 4) << 2) + j;
        int col = (int)tn + wc * 64 + n * 16 + (lane & 15);
        float v = acc[m][n][j] + b_ih[col] + b_hh[col];
        C[row * 4096 + col] = f2bf(v);
      }
}

// ---------------- persistent LSTM scan ----------------
// 128 blocks x 512 threads (8 waves). Block b owns units u0=b*8 (32 weight
// rows = 8 units x 4 gates), held entirely in registers for all 256 steps.
// Waves: (stripe s4 = w&3 over batch, K-half kh = w>>2). Per step each wave:
// 16 A-frag loads of h (global, L2-hot) + 32 MFMA. Partials combined in LDS.
// c-state lives in one register per thread for the whole scan.
__global__ __launch_bounds__(512, 2) void lstm_scan(
    const ushort_t* __restrict__ whhb,   // W_hh bf16 [4096][1024]
    const ushort_t* __restrict__ xproj,  // bf16 [16384][4096]
    const float* __restrict__ reset,     // f32 [256*64]
    const float* __restrict__ cx,        // f32 [64*1024]
    ushort_t* __restrict__ h0buf, ushort_t* __restrict__ h1buf,
    float* __restrict__ out_h0, float* __restrict__ out_h1,
    float* __restrict__ out_cs)
{
  __shared__ float gsh[16 * 256];   // [kh][stripe][col][16x16] partial gates
  const int t = threadIdx.x;
  const int lane = t & 63;
  const int w = t >> 6;
  const int s4 = w & 3;      // batch stripe (16 rows)
  const int kh = w >> 2;     // K half (512)
  const int j = lane & 15;   // fragment row
  const int q = lane >> 4;   // k subchunk
  const int u0 = blockIdx.x * 8;

  // ---- load weight fragments into registers (permanent) ----
  s16x8 bfrag[2][16];
#pragma unroll
  for (int col = 0; col < 2; col++) {
    int lw = col * 16 + j;                       // local weight row 0..31
    const ushort_t* wrow = whhb + ((size_t)((lw >> 3) * 1024 + u0 + (lw & 7))) * 1024
                          + kh * 512 + q * 8;
#pragma unroll
    for (int kk = 0; kk < 16; kk++)
      bfrag[col][kk] = *(const s16x8*)(wrow + kk * 32);
  }

  // ---- persistent cell state ----
  const int bb = t >> 3;     // batch 0..63
  const int uu = t & 7;      // unit within block
  float c_reg = cx[(size_t)bb * 1024 + u0 + uu];

  cooperative_groups::grid_group grid = cooperative_groups::this_grid();
  const s16x8 zv = {0, 0, 0, 0, 0, 0, 0, 0};

  for (int s = 0; s < 256; s++) {
    const ushort_t* hc = (s & 1) ? h1buf : h0buf;
    ushort_t* hn = (s & 1) ? h0buf : h1buf;

    // mask for this lane's A row (reset is exactly 0/1)
    float rr = reset[s * 64 + s4 * 16 + j];
    bool mz = (rr != 0.0f);

    f32x4 acc0 = {0.f, 0.f, 0.f, 0.f}, acc1 = {0.f, 0.f, 0.f, 0.f};
    const ushort_t* hrow = hc + (size_t)(s4 * 16 + j) * 1024 + kh * 512 + q * 8;
#pragma unroll
    for (int kk = 0; kk < 16; kk++) {
      s16x8 a = *(const s16x8*)(hrow + kk * 32);
      if (mz) a = zv;
      acc0 = __builtin_amdgcn_mfma_f32_16x16x32_bf16(a, bfrag[0][kk], acc0, 0, 0, 0);
      acc1 = __builtin_amdgcn_mfma_f32_16x16x32_bf16(a, bfrag[1][kk], acc1, 0, 0, 0);
    }

    // stash partials: slot = ((kh*4 + s4)*2 + col), C layout: col=lane&15, row=q*4+jj
    int sbase = ((kh * 4 + s4) * 2) * 256;
#pragma unroll
    for (int jj = 0; jj < 4; jj++) {
      gsh[sbase + (q * 4 + jj) * 16 + j] = acc0[jj];
      gsh[sbase + 256 + (q * 4 + jj) * 16 + j] = acc1[jj];
    }
    __syncthreads();

    // ---- cell update: one (batch, unit) per thread ----
    float m2 = 1.0f - reset[s * 64 + bb];
    float gv[4];
#pragma unroll
    for (int g = 0; g < 4; g++) {
      int lw = g * 8 + uu;
      int ct = lw >> 4, cc = lw & 15;
      int o = (((bb >> 4) * 2) + ct) * 256 + (bb & 15) * 16 + cc;
      gv[g] = gsh[o] + gsh[2048 + o]
            + bf2f(xproj[((size_t)s * 64 + bb) * 4096 + g * 1024 + u0 + uu]);
    }
    float ii = sigm(gv[0]), ff = sigm(gv[1]), G = tanh_f(gv[2]), oo = sigm(gv[3]);
    float cp = c_reg * m2;
    float cn = ff * cp + ii * G;
    float hnv = oo * tanh_f(cn);
    c_reg = cn;

    size_t ob = ((size_t)s * 64 + bb) * 1024 + u0 + uu;
    out_cs[ob] = cn;
    out_h0[ob] = hnv;
    out_h1[ob] = hnv;
    // agent-scope store so h_next is at the coherence point before the barrier
    __hip_atomic_store(&hn[bb * 1024 + u0 + uu], f2bf(hnv),
                       __ATOMIC_RELAXED, __HIP_MEMORY_SCOPE_AGENT);

    if (s < 255) grid.sync();
  }
}

extern "C" void kernel_launch(void* const* d_in, const int* in_sizes, int n_in,
                              void* d_out, int out_size, void* d_ws, size_t ws_size,
                              hipStream_t stream) {
  const float* x     = (const float*)d_in[0];
  const float* hx    = (const float*)d_in[1];
  const float* cx    = (const float*)d_in[2];
  const float* reset = (const float*)d_in[3];
  const float* W_ih  = (const float*)d_in[4];
  const float* W_hh  = (const float*)d_in[5];
  const float* b_ih  = (const float*)d_in[6];
  const float* b_hh  = (const float*)d_in[7];
  float* out = (float*)d_out;

  char* ws = (char*)d_ws;
  ushort_t* xbf   = (ushort_t*)(ws);                  // 33,554,432 B
  ushort_t* wihb  = (ushort_t*)(ws + 33554432);       //  8,388,608 B
  ushort_t* whhb  = (ushort_t*)(ws + 41943040);       //  8,388,608 B
  ushort_t* xproj = (ushort_t*)(ws + 50331648);       // 134,217,728 B
  ushort_t* h0    = (ushort_t*)(ws + 184549376);      // 131,072 B
  ushort_t* h1    = (ushort_t*)(ws + 184680448);      // 131,072 B

  hipLaunchKernelGGL(conv_f32_to_bf16, dim3(16384), dim3(256), 0, stream, x, xbf, 4194304);
  hipLaunchKernelGGL(conv_f32_to_bf16, dim3(4096), dim3(256), 0, stream, W_ih, wihb, 1048576);
  hipLaunchKernelGGL(conv_f32_to_bf16, dim3(4096), dim3(256), 0, stream, W_hh, whhb, 1048576);
  hipLaunchKernelGGL(init_h, dim3(256), dim3(256), 0, stream, hx, h0, 65536);
  hipLaunchKernelGGL(gemm_xproj, dim3(128, 32), dim3(256), 0, stream, xbf, wihb, b_ih, b_hh, xproj);

  float* oh0 = out;
  float* oh1 = out + 16777216;
  float* ocs = out + 33554432;

  const ushort_t* whhb_c = whhb;
  const ushort_t* xproj_c = xproj;
  void* args[] = {(void*)&whhb_c, (void*)&xproj_c, (void*)&reset, (void*)&cx,
                  (void*)&h0, (void*)&h1, (void*)&oh0, (void*)&oh1, (void*)&ocs};
  hipLaunchCooperativeKernel((void*)lstm_scan, dim3(128), dim3(512), args, 0, stream);
}

// Round 3
// 4038.514 us; speedup vs baseline: 1.4399x; 1.4399x over previous
//
#include <hip/hip_runtime.h>
#include <stdint.h>

// SEQ=256, B=64, DIM=1024, UNITS=1024, 4U=4096
typedef unsigned short ushort_t;
typedef __attribute__((ext_vector_type(8))) short s16x8;
typedef __attribute__((ext_vector_type(4))) float f32x4;
typedef __attribute__((ext_vector_type(4))) unsigned short u16x4;

#define TO_GLB(p) ((const __attribute__((address_space(1))) void*)(p))
#define TO_LDS(p) ((__attribute__((address_space(3))) void*)(p))

__device__ __forceinline__ ushort_t f2bf(float f) {
  union { float f; uint32_t u; } v; v.f = f;
  uint32_t u = v.u;
  uint32_t r = (u + 0x7FFFu + ((u >> 16) & 1u)) >> 16;
  return (ushort_t)r;
}
__device__ __forceinline__ float bf2f(ushort_t b) {
  union { uint32_t u; float f; } v; v.u = ((uint32_t)b) << 16;
  return v.f;
}
__device__ __forceinline__ float sigm(float x) {
  x = fminf(fmaxf(x, -30.f), 30.f);
  return 1.0f / (1.0f + __expf(-x));
}
__device__ __forceinline__ float tanh_f(float x) {
  x = fminf(fmaxf(x, -15.f), 15.f);
  float t = __expf(2.0f * x);
  return (t - 1.0f) / (t + 1.0f);
}

// ---------------- convert f32 -> bf16, 4 elems/thread ----------------
__global__ void conv_f32_to_bf16(const float* __restrict__ src,
                                 ushort_t* __restrict__ dst, int n4) {
  int i = blockIdx.x * blockDim.x + threadIdx.x;
  if (i < n4) {
    float4 v = ((const float4*)src)[i];
    u16x4 o;
    o[0] = f2bf(v.x); o[1] = f2bf(v.y); o[2] = f2bf(v.z); o[3] = f2bf(v.w);
    *(u16x4*)(dst + 4 * (size_t)i) = o;
  }
}

// ---------------- init h0 (bf16) from hx ----------------
__global__ void init_h(const float* __restrict__ hx, ushort_t* __restrict__ h0, int n) {
  int i = blockIdx.x * blockDim.x + threadIdx.x;
  if (i < n) h0[i] = f2bf(hx[i]);
}

// ---------------- x_proj GEMM: C[16384][4096] = A @ W_ih^T + b_ih + b_hh ----
__global__ __launch_bounds__(256) void gemm_xproj(
    const ushort_t* __restrict__ A,   // x bf16 [16384][1024]
    const ushort_t* __restrict__ Bw,  // W_ih bf16 [4096][1024]
    const float* __restrict__ b_ih, const float* __restrict__ b_hh,
    ushort_t* __restrict__ C)         // x_proj bf16 [16384][4096]
{
  __shared__ ushort_t As[128 * 32];
  __shared__ ushort_t Bs[128 * 32];
  const int t = threadIdx.x;
  const int lane = t & 63;
  const int wid = t >> 6;
  const int wr = wid >> 1, wc = wid & 1;
  const size_t tm = (size_t)blockIdx.x * 128;
  const size_t tn = (size_t)blockIdx.y * 128;

  f32x4 acc[4][4];
  const f32x4 zero = {0.f, 0.f, 0.f, 0.f};
#pragma unroll
  for (int m = 0; m < 4; m++)
#pragma unroll
    for (int n = 0; n < 4; n++) acc[m][n] = zero;

  for (int k0 = 0; k0 < 1024; k0 += 32) {
    __syncthreads();
#pragma unroll
    for (int i = 0; i < 2; i++) {
      int row = i * 64 + (t >> 2);
      int kc = (t & 3) * 8;
      const ushort_t* ga = A + (tm + row) * 1024 + k0 + kc;
      __builtin_amdgcn_global_load_lds(TO_GLB(ga),
          TO_LDS((char*)As + (i * 256 + wid * 64) * 16), 16, 0, 0);
      const ushort_t* gb = Bw + (tn + row) * 1024 + k0 + kc;
      __builtin_amdgcn_global_load_lds(TO_GLB(gb),
          TO_LDS((char*)Bs + (i * 256 + wid * 64) * 16), 16, 0, 0);
    }
    __syncthreads();
    s16x8 af[4], bfr[4];
#pragma unroll
    for (int m = 0; m < 4; m++) {
      int r = wr * 64 + m * 16 + (lane & 15);
      af[m] = *(const s16x8*)((const char*)As + r * 64 + (lane >> 4) * 16);
    }
#pragma unroll
    for (int n = 0; n < 4; n++) {
      int r = wc * 64 + n * 16 + (lane & 15);
      bfr[n] = *(const s16x8*)((const char*)Bs + r * 64 + (lane >> 4) * 16);
    }
#pragma unroll
    for (int m = 0; m < 4; m++)
#pragma unroll
      for (int n = 0; n < 4; n++)
        acc[m][n] = __builtin_amdgcn_mfma_f32_16x16x32_bf16(af[m], bfr[n], acc[m][n], 0, 0, 0);
  }

#pragma unroll
  for (int m = 0; m < 4; m++)
#pragma unroll
    for (int n = 0; n < 4; n++)
#pragma unroll
      for (int j = 0; j < 4; j++) {
        size_t row = tm + wr * 64 + m * 16 + ((lane >> 4) << 2) + j;
        int col = (int)tn + wc * 64 + n * 16 + (lane & 15);
        float v = acc[m][n][j] + b_ih[col] + b_hh[col];
        C[row * 4096 + col] = f2bf(v);
      }
}

// ---------------- persistent LSTM scan, data-flow sync ----------------
// 128 blocks = 4 batch-groups x 32 unit-groups; 512 threads (8 waves).
// Block owns [16 batch rows x 32 units]: W_hh rows {g*1024+u0..+32, g=0..3}
// (128 rows) in registers (32 s16x8/thread), c-state in 1 reg/thread.
// Per step: poll 32 producer flags (own batch-group) -> stage h[16][1024]
// to LDS (agent-scope loads, XOR swizzle) -> 32 MFMA/wave full-K ->
// gates via LDS -> cell update -> agent-scope h stores -> release flag.
__global__ __launch_bounds__(512, 2) void lstm_scan(
    const ushort_t* __restrict__ whhb,   // W_hh bf16 [4096][1024]
    const ushort_t* __restrict__ xproj,  // bf16 [16384][4096]
    const float* __restrict__ reset,     // f32 [256*64]
    const float* __restrict__ cx,        // f32 [64*1024]
    ushort_t* __restrict__ h0buf, ushort_t* __restrict__ h1buf,
    unsigned int* __restrict__ flags,    // [128], zeroed before launch
    float* __restrict__ out_h0, float* __restrict__ out_h1,
    float* __restrict__ out_cs)
{
  __shared__ char smem[40960];
  char* hs = smem;                        // h tile [16][2048B], XOR-swizzled
  float* gsh = (float*)(smem + 32768);    // gates [16][128], col-swizzled

  const int t = threadIdx.x;
  const int lane = t & 63;
  const int w = t >> 6;
  const int j16 = lane & 15;
  const int q = lane >> 4;
  const int blk = blockIdx.x;
  const int bg = blk >> 5;       // batch group 0..3
  const int ug = blk & 31;       // unit group 0..31
  const int b0 = bg * 16;
  const int u0 = ug * 32;

  // ---- permanent weight fragments: wave w owns gate-rows lr = w*16..+16 ----
  s16x8 bfrag[32];
  {
    int lr = w * 16 + j16;
    int g = lr >> 5, lu = lr & 31;
    const ushort_t* wrow = whhb + ((size_t)(g * 1024 + u0 + lu)) * 1024 + q * 8;
#pragma unroll
    for (int kk = 0; kk < 32; kk++)
      bfrag[kk] = *(const s16x8*)(wrow + kk * 32);
  }

  // ---- persistent cell state: thread owns (b_local, lu_t) ----
  const int b_local = t >> 5;    // 0..15
  const int lu_t = t & 31;       // 0..31
  float c_reg = cx[(size_t)(b0 + b_local) * 1024 + u0 + lu_t];

  // staging coords: thread loads row sr, 64B chunk sc
  const int sr = t & 15;
  const int sc = t >> 4;

  for (int s = 0; s < 256; s++) {
    const ushort_t* hc = (s & 1) ? h1buf : h0buf;
    ushort_t* hn = (s & 1) ? h0buf : h1buf;

    // prefetch xproj/reset for this step (independent of h -> hides under poll)
    const size_t xb = ((size_t)s * 64 + b0 + b_local) * 4096 + u0 + lu_t;
    ushort_t xp0 = xproj[xb];
    ushort_t xp1 = xproj[xb + 1024];
    ushort_t xp2 = xproj[xb + 2048];
    ushort_t xp3 = xproj[xb + 3072];
    float m2 = 1.0f - reset[s * 64 + b0 + b_local];
    float mrow = reset[s * 64 + b0 + sr];

    // ---- wait for the 32 producers of our batch-group (skip at s=0) ----
    if (s > 0) {
      if (w == 0 && lane < 32) {
        const unsigned int* fp = flags + bg * 32 + lane;
        while (__hip_atomic_load(fp, __ATOMIC_RELAXED, __HIP_MEMORY_SCOPE_AGENT)
               < (unsigned int)s) {}
      }
      __syncthreads();
      __builtin_amdgcn_fence(__ATOMIC_ACQUIRE, "agent");
    }

    // ---- stage h[16][1024] -> LDS (agent-scope 8B loads bypass stale L2) ----
    {
      const char* src = (const char*)(hc + (size_t)(b0 + sr) * 1024 + sc * 32);
#pragma unroll
      for (int jj = 0; jj < 8; jj++) {
        unsigned long long v = __hip_atomic_load(
            (const unsigned long long*)(src + jj * 8),
            __ATOMIC_RELAXED, __HIP_MEMORY_SCOPE_AGENT);
        if (mrow != 0.0f) v = 0ull;   // episode reset: h := 0
        int off = (sr * 2048 + sc * 64 + jj * 8) ^ ((sr & 7) << 4);
        *(unsigned long long*)(hs + off) = v;
      }
    }
    __syncthreads();

    // ---- full-K MFMA: wave computes gates[16 batch][16 gate-rows] ----
    f32x4 acc0 = {0.f, 0.f, 0.f, 0.f}, acc1 = {0.f, 0.f, 0.f, 0.f};
#pragma unroll
    for (int kk = 0; kk < 32; kk += 2) {
      int off0 = (j16 * 2048 + kk * 64 + q * 16) ^ ((j16 & 7) << 4);
      int off1 = (j16 * 2048 + (kk + 1) * 64 + q * 16) ^ ((j16 & 7) << 4);
      s16x8 a0 = *(const s16x8*)(hs + off0);
      s16x8 a1 = *(const s16x8*)(hs + off1);
      acc0 = __builtin_amdgcn_mfma_f32_16x16x32_bf16(a0, bfrag[kk], acc0, 0, 0, 0);
      acc1 = __builtin_amdgcn_mfma_f32_16x16x32_bf16(a1, bfrag[kk + 1], acc1, 0, 0, 0);
    }

    // ---- stash gates: gsh[row][col ^ ((row&7)<<2)], row=batch, col=gate-row ----
#pragma unroll
    for (int jj = 0; jj < 4; jj++) {
      int row = q * 4 + jj;
      int col = (w * 16 + j16) ^ ((row & 7) << 2);
      gsh[row * 128 + col] = acc0[jj] + acc1[jj];
    }
    __syncthreads();

    // ---- cell update ----
    float gv0 = gsh[b_local * 128 + ((0 * 32 + lu_t) ^ ((b_local & 7) << 2))] + bf2f(xp0);
    float gv1 = gsh[b_local * 128 + ((1 * 32 + lu_t) ^ ((b_local & 7) << 2))] + bf2f(xp1);
    float gv2 = gsh[b_local * 128 + ((2 * 32 + lu_t) ^ ((b_local & 7) << 2))] + bf2f(xp2);
    float gv3 = gsh[b_local * 128 + ((3 * 32 + lu_t) ^ ((b_local & 7) << 2))] + bf2f(xp3);
    float ii = sigm(gv0), ff = sigm(gv1), G = tanh_f(gv2), oo = sigm(gv3);
    float cn = ff * (c_reg * m2) + ii * G;
    float hv = oo * tanh_f(cn);
    c_reg = cn;

    size_t ob = ((size_t)s * 64 + b0 + b_local) * 1024 + u0 + lu_t;
    out_cs[ob] = cn;
    out_h0[ob] = hv;
    out_h1[ob] = hv;
    // write-through h (sc1) so it's at the coherence point before the flag
    __hip_atomic_store(&hn[(size_t)(b0 + b_local) * 1024 + u0 + lu_t], f2bf(hv),
                       __ATOMIC_RELAXED, __HIP_MEMORY_SCOPE_AGENT);

    __syncthreads();   // drains every thread's vmcnt before the flag
    if (t == 0)
      __hip_atomic_store(&flags[blk], (unsigned int)(s + 1),
                         __ATOMIC_RELEASE, __HIP_MEMORY_SCOPE_AGENT);
  }
}

extern "C" void kernel_launch(void* const* d_in, const int* in_sizes, int n_in,
                              void* d_out, int out_size, void* d_ws, size_t ws_size,
                              hipStream_t stream) {
  const float* x     = (const float*)d_in[0];
  const float* hx    = (const float*)d_in[1];
  const float* cx    = (const float*)d_in[2];
  const float* reset = (const float*)d_in[3];
  const float* W_ih  = (const float*)d_in[4];
  const float* W_hh  = (const float*)d_in[5];
  const float* b_ih  = (const float*)d_in[6];
  const float* b_hh  = (const float*)d_in[7];
  float* out = (float*)d_out;

  char* ws = (char*)d_ws;
  ushort_t* xbf   = (ushort_t*)(ws);                  // 33,554,432 B
  ushort_t* wihb  = (ushort_t*)(ws + 33554432);       //  8,388,608 B
  ushort_t* whhb  = (ushort_t*)(ws + 41943040);       //  8,388,608 B
  ushort_t* xproj = (ushort_t*)(ws + 50331648);       // 134,217,728 B
  ushort_t* h0    = (ushort_t*)(ws + 184549376);      // 131,072 B
  ushort_t* h1    = (ushort_t*)(ws + 184680448);      // 131,072 B
  unsigned int* flags = (unsigned int*)(ws + 184811520);  // 512 B

  hipMemsetAsync(flags, 0, 128 * sizeof(unsigned int), stream);
  hipLaunchKernelGGL(conv_f32_to_bf16, dim3(16384), dim3(256), 0, stream, x, xbf, 4194304);
  hipLaunchKernelGGL(conv_f32_to_bf16, dim3(4096), dim3(256), 0, stream, W_ih, wihb, 1048576);
  hipLaunchKernelGGL(conv_f32_to_bf16, dim3(4096), dim3(256), 0, stream, W_hh, whhb, 1048576);
  hipLaunchKernelGGL(init_h, dim3(256), dim3(256), 0, stream, hx, h0, 65536);
  hipLaunchKernelGGL(gemm_xproj, dim3(128, 32), dim3(256), 0, stream, xbf, wihb, b_ih, b_hh, xproj);

  float* oh0 = out;
  float* oh1 = out + 16777216;
  float* ocs = out + 33554432;

  const ushort_t* whhb_c = whhb;
  const ushort_t* xproj_c = xproj;
  void* args[] = {(void*)&whhb_c, (void*)&xproj_c, (void*)&reset, (void*)&cx,
                  (void*)&h0, (void*)&h1, (void*)&flags,
                  (void*)&oh0, (void*)&oh1, (void*)&ocs};
  hipLaunchCooperativeKernel((void*)lstm_scan, dim3(128), dim3(512), args, 0, stream);
}

// Round 4
// 1517.843 us; speedup vs baseline: 3.8312x; 2.6607x over previous
//
#include <hip/hip_runtime.h>
#include <stdint.h>

// SEQ=256, B=64, DIM=1024, UNITS=1024, 4U=4096
typedef unsigned short ushort_t;
typedef __attribute__((ext_vector_type(8))) short s16x8;
typedef __attribute__((ext_vector_type(4))) float f32x4;
typedef __attribute__((ext_vector_type(4))) unsigned short u16x4;

#define TO_GLB(p) ((const __attribute__((address_space(1))) void*)(p))
#define TO_LDS(p) ((__attribute__((address_space(3))) void*)(p))

__device__ __forceinline__ ushort_t f2bf(float f) {
  union { float f; uint32_t u; } v; v.f = f;
  uint32_t u = v.u;
  uint32_t r = (u + 0x7FFFu + ((u >> 16) & 1u)) >> 16;
  return (ushort_t)r;
}
__device__ __forceinline__ float bf2f(ushort_t b) {
  union { uint32_t u; float f; } v; v.u = ((uint32_t)b) << 16;
  return v.f;
}
__device__ __forceinline__ float sigm(float x) {
  x = fminf(fmaxf(x, -30.f), 30.f);
  return 1.0f / (1.0f + __expf(-x));
}
__device__ __forceinline__ float tanh_f(float x) {
  x = fminf(fmaxf(x, -15.f), 15.f);
  float t = __expf(2.0f * x);
  return (t - 1.0f) / (t + 1.0f);
}

// ---------------- convert f32 -> bf16, 4 elems/thread ----------------
__global__ void conv_f32_to_bf16(const float* __restrict__ src,
                                 ushort_t* __restrict__ dst, int n4) {
  int i = blockIdx.x * blockDim.x + threadIdx.x;
  if (i < n4) {
    float4 v = ((const float4*)src)[i];
    u16x4 o;
    o[0] = f2bf(v.x); o[1] = f2bf(v.y); o[2] = f2bf(v.z); o[3] = f2bf(v.w);
    *(u16x4*)(dst + 4 * (size_t)i) = o;
  }
}

// ---------------- init h0 (bf16) from hx ----------------
__global__ void init_h(const float* __restrict__ hx, ushort_t* __restrict__ h0, int n) {
  int i = blockIdx.x * blockDim.x + threadIdx.x;
  if (i < n) h0[i] = f2bf(hx[i]);
}

// ---------------- x_proj GEMM: C[16384][4096] = A @ W_ih^T + b_ih + b_hh ----
__global__ __launch_bounds__(256) void gemm_xproj(
    const ushort_t* __restrict__ A,   // x bf16 [16384][1024]
    const ushort_t* __restrict__ Bw,  // W_ih bf16 [4096][1024]
    const float* __restrict__ b_ih, const float* __restrict__ b_hh,
    ushort_t* __restrict__ C)         // x_proj bf16 [16384][4096]
{
  __shared__ ushort_t As[128 * 32];
  __shared__ ushort_t Bs[128 * 32];
  const int t = threadIdx.x;
  const int lane = t & 63;
  const int wid = t >> 6;
  const int wr = wid >> 1, wc = wid & 1;
  const size_t tm = (size_t)blockIdx.x * 128;
  const size_t tn = (size_t)blockIdx.y * 128;

  f32x4 acc[4][4];
  const f32x4 zero = {0.f, 0.f, 0.f, 0.f};
#pragma unroll
  for (int m = 0; m < 4; m++)
#pragma unroll
    for (int n = 0; n < 4; n++) acc[m][n] = zero;

  for (int k0 = 0; k0 < 1024; k0 += 32) {
    __syncthreads();
#pragma unroll
    for (int i = 0; i < 2; i++) {
      int row = i * 64 + (t >> 2);
      int kc = (t & 3) * 8;
      const ushort_t* ga = A + (tm + row) * 1024 + k0 + kc;
      __builtin_amdgcn_global_load_lds(TO_GLB(ga),
          TO_LDS((char*)As + (i * 256 + wid * 64) * 16), 16, 0, 0);
      const ushort_t* gb = Bw + (tn + row) * 1024 + k0 + kc;
      __builtin_amdgcn_global_load_lds(TO_GLB(gb),
          TO_LDS((char*)Bs + (i * 256 + wid * 64) * 16), 16, 0, 0);
    }
    __syncthreads();
    s16x8 af[4], bfr[4];
#pragma unroll
    for (int m = 0; m < 4; m++) {
      int r = wr * 64 + m * 16 + (lane & 15);
      af[m] = *(const s16x8*)((const char*)As + r * 64 + (lane >> 4) * 16);
    }
#pragma unroll
    for (int n = 0; n < 4; n++) {
      int r = wc * 64 + n * 16 + (lane & 15);
      bfr[n] = *(const s16x8*)((const char*)Bs + r * 64 + (lane >> 4) * 16);
    }
#pragma unroll
    for (int m = 0; m < 4; m++)
#pragma unroll
      for (int n = 0; n < 4; n++)
        acc[m][n] = __builtin_amdgcn_mfma_f32_16x16x32_bf16(af[m], bfr[n], acc[m][n], 0, 0, 0);
  }

#pragma unroll
  for (int m = 0; m < 4; m++)
#pragma unroll
    for (int n = 0; n < 4; n++)
#pragma unroll
      for (int j = 0; j < 4; j++) {
        size_t row = tm + wr * 64 + m * 16 + ((lane >> 4) << 2) + j;
        int col = (int)tn + wc * 64 + n * 16 + (lane & 15);
        float v = acc[m][n][j] + b_ih[col] + b_hh[col];
        C[row * 4096 + col] = f2bf(v);
      }
}

// ---------------- persistent LSTM scan, data-flow sync (fence-free) -------
// 128 blocks = 4 batch-groups x 32 unit-groups; 512 threads (8 waves).
// All cross-block traffic (h, flags) uses sc1 (agent-scope) accesses that
// meet at the Infinity Cache: producer h stores are write-through, drained
// by an explicit vmcnt(0) before the RELAXED flag store; consumer poll load
// + branch orders the subsequent sc1 h loads. No acquire fence (no
// buffer_inv), no release writeback.
__global__ __launch_bounds__(512, 2) void lstm_scan(
    const ushort_t* __restrict__ whhb,   // W_hh bf16 [4096][1024]
    const ushort_t* __restrict__ xproj,  // bf16 [16384][4096]
    const float* __restrict__ reset,     // f32 [256*64]
    const float* __restrict__ cx,        // f32 [64*1024]
    ushort_t* __restrict__ h0buf, ushort_t* __restrict__ h1buf,
    unsigned int* __restrict__ flags,    // [128], zeroed before launch
    float* __restrict__ out_h0, float* __restrict__ out_h1,
    float* __restrict__ out_cs)
{
  __shared__ char smem[40960];
  char* hs = smem;                        // h tile [16][2048B], XOR-swizzled
  float* gsh = (float*)(smem + 32768);    // gates [16][128], col-swizzled

  const int t = threadIdx.x;
  const int lane = t & 63;
  const int w = t >> 6;
  const int j16 = lane & 15;
  const int q = lane >> 4;
  const int blk = blockIdx.x;
  const int bg = blk >> 5;       // batch group 0..3
  const int ug = blk & 31;       // unit group 0..31
  const int b0 = bg * 16;
  const int u0 = ug * 32;

  // ---- permanent weight fragments: wave w owns gate-rows lr = w*16..+16 ----
  s16x8 bfrag[32];
  {
    int lr = w * 16 + j16;
    int g = lr >> 5, lu = lr & 31;
    const ushort_t* wrow = whhb + ((size_t)(g * 1024 + u0 + lu)) * 1024 + q * 8;
#pragma unroll
    for (int kk = 0; kk < 32; kk++)
      bfrag[kk] = *(const s16x8*)(wrow + kk * 32);
  }

  // ---- persistent cell state: thread owns (b_local, lu_t) ----
  const int b_local = t >> 5;    // 0..15
  const int lu_t = t & 31;       // 0..31
  float c_reg = cx[(size_t)(b0 + b_local) * 1024 + u0 + lu_t];

  // staging coords: thread loads row sr, 64B chunk sc
  const int sr = t & 15;
  const int sc = t >> 4;

  for (int s = 0; s < 256; s++) {
    const ushort_t* hc = (s & 1) ? h1buf : h0buf;
    ushort_t* hn = (s & 1) ? h0buf : h1buf;

    // prefetch xproj/reset for this step (independent of h -> hides under poll)
    const size_t xb = ((size_t)s * 64 + b0 + b_local) * 4096 + u0 + lu_t;
    ushort_t xp0 = xproj[xb];
    ushort_t xp1 = xproj[xb + 1024];
    ushort_t xp2 = xproj[xb + 2048];
    ushort_t xp3 = xproj[xb + 3072];
    float m2 = 1.0f - reset[s * 64 + b0 + b_local];
    float mrow = reset[s * 64 + b0 + sr];

    // ---- wait for the 32 producers of our batch-group (skip at s=0) ----
    if (s > 0) {
      if (w == 0 && lane < 32) {
        const unsigned int* fp = flags + bg * 32 + lane;
        while (__hip_atomic_load(fp, __ATOMIC_RELAXED, __HIP_MEMORY_SCOPE_AGENT)
               < (unsigned int)s) {}
      }
      __syncthreads();   // also a compiler barrier: h loads stay below the poll
    }

    // ---- stage h[16][1024] -> LDS (sc1 8B loads meet producer at the LLC) ----
    {
      const char* src = (const char*)(hc + (size_t)(b0 + sr) * 1024 + sc * 32);
#pragma unroll
      for (int jj = 0; jj < 8; jj++) {
        unsigned long long v = __hip_atomic_load(
            (const unsigned long long*)(src + jj * 8),
            __ATOMIC_RELAXED, __HIP_MEMORY_SCOPE_AGENT);
        if (mrow != 0.0f) v = 0ull;   // episode reset: h := 0
        int off = (sr * 2048 + sc * 64 + jj * 8) ^ ((sr & 7) << 4);
        *(unsigned long long*)(hs + off) = v;
      }
    }
    __syncthreads();

    // ---- full-K MFMA: wave computes gates[16 batch][16 gate-rows] ----
    f32x4 acc0 = {0.f, 0.f, 0.f, 0.f}, acc1 = {0.f, 0.f, 0.f, 0.f};
#pragma unroll
    for (int kk = 0; kk < 32; kk += 2) {
      int off0 = (j16 * 2048 + kk * 64 + q * 16) ^ ((j16 & 7) << 4);
      int off1 = (j16 * 2048 + (kk + 1) * 64 + q * 16) ^ ((j16 & 7) << 4);
      s16x8 a0 = *(const s16x8*)(hs + off0);
      s16x8 a1 = *(const s16x8*)(hs + off1);
      acc0 = __builtin_amdgcn_mfma_f32_16x16x32_bf16(a0, bfrag[kk], acc0, 0, 0, 0);
      acc1 = __builtin_amdgcn_mfma_f32_16x16x32_bf16(a1, bfrag[kk + 1], acc1, 0, 0, 0);
    }

    // ---- stash gates: gsh[row][col ^ ((row&7)<<2)], row=batch, col=gate-row ----
#pragma unroll
    for (int jj = 0; jj < 4; jj++) {
      int row = q * 4 + jj;
      int col = (w * 16 + j16) ^ ((row & 7) << 2);
      gsh[row * 128 + col] = acc0[jj] + acc1[jj];
    }
    __syncthreads();

    // ---- cell update ----
    float gv0 = gsh[b_local * 128 + ((0 * 32 + lu_t) ^ ((b_local & 7) << 2))] + bf2f(xp0);
    float gv1 = gsh[b_local * 128 + ((1 * 32 + lu_t) ^ ((b_local & 7) << 2))] + bf2f(xp1);
    float gv2 = gsh[b_local * 128 + ((2 * 32 + lu_t) ^ ((b_local & 7) << 2))] + bf2f(xp2);
    float gv3 = gsh[b_local * 128 + ((3 * 32 + lu_t) ^ ((b_local & 7) << 2))] + bf2f(xp3);
    float ii = sigm(gv0), ff = sigm(gv1), G = tanh_f(gv2), oo = sigm(gv3);
    float cn = ff * (c_reg * m2) + ii * G;
    float hv = oo * tanh_f(cn);
    c_reg = cn;

    size_t ob = ((size_t)s * 64 + b0 + b_local) * 1024 + u0 + lu_t;
    out_cs[ob] = cn;
    out_h0[ob] = hv;
    out_h1[ob] = hv;

    // ---- h store: pack lane-pairs to one 4B agent-scope (sc1) store ----
    {
      unsigned int mybits = (unsigned int)f2bf(hv);
      unsigned int pb = (unsigned int)__shfl_xor((int)mybits, 1, 64);
      if ((t & 1) == 0) {
        unsigned int pack = mybits | (pb << 16);
        __hip_atomic_store(
            (unsigned int*)(hn + (size_t)(b0 + b_local) * 1024 + u0 + lu_t),
            pack, __ATOMIC_RELAXED, __HIP_MEMORY_SCOPE_AGENT);
      }
    }

    // drain this thread's stores, join all waves, then RELAXED flag release
    asm volatile("s_waitcnt vmcnt(0)" ::: "memory");
    __syncthreads();
    if (t == 0)
      __hip_atomic_store(&flags[blk], (unsigned int)(s + 1),
                         __ATOMIC_RELAXED, __HIP_MEMORY_SCOPE_AGENT);
  }
}

extern "C" void kernel_launch(void* const* d_in, const int* in_sizes, int n_in,
                              void* d_out, int out_size, void* d_ws, size_t ws_size,
                              hipStream_t stream) {
  const float* x     = (const float*)d_in[0];
  const float* hx    = (const float*)d_in[1];
  const float* cx    = (const float*)d_in[2];
  const float* reset = (const float*)d_in[3];
  const float* W_ih  = (const float*)d_in[4];
  const float* W_hh  = (const float*)d_in[5];
  const float* b_ih  = (const float*)d_in[6];
  const float* b_hh  = (const float*)d_in[7];
  float* out = (float*)d_out;

  char* ws = (char*)d_ws;
  ushort_t* xbf   = (ushort_t*)(ws);                  // 33,554,432 B
  ushort_t* wihb  = (ushort_t*)(ws + 33554432);       //  8,388,608 B
  ushort_t* whhb  = (ushort_t*)(ws + 41943040);       //  8,388,608 B
  ushort_t* xproj = (ushort_t*)(ws + 50331648);       // 134,217,728 B
  ushort_t* h0    = (ushort_t*)(ws + 184549376);      // 131,072 B
  ushort_t* h1    = (ushort_t*)(ws + 184680448);      // 131,072 B
  unsigned int* flags = (unsigned int*)(ws + 184811520);  // 512 B

  hipMemsetAsync(flags, 0, 128 * sizeof(unsigned int), stream);
  hipLaunchKernelGGL(conv_f32_to_bf16, dim3(16384), dim3(256), 0, stream, x, xbf, 4194304);
  hipLaunchKernelGGL(conv_f32_to_bf16, dim3(4096), dim3(256), 0, stream, W_ih, wihb, 1048576);
  hipLaunchKernelGGL(conv_f32_to_bf16, dim3(4096), dim3(256), 0, stream, W_hh, whhb, 1048576);
  hipLaunchKernelGGL(init_h, dim3(256), dim3(256), 0, stream, hx, h0, 65536);
  hipLaunchKernelGGL(gemm_xproj, dim3(128, 32), dim3(256), 0, stream, xbf, wihb, b_ih, b_hh, xproj);

  float* oh0 = out;
  float* oh1 = out + 16777216;
  float* ocs = out + 33554432;

  const ushort_t* whhb_c = whhb;
  const ushort_t* xproj_c = xproj;
  void* args[] = {(void*)&whhb_c, (void*)&xproj_c, (void*)&reset, (void*)&cx,
                  (void*)&h0, (void*)&h1, (void*)&flags,
                  (void*)&oh0, (void*)&oh1, (void*)&ocs};
  hipLaunchCooperativeKernel((void*)lstm_scan, dim3(128), dim3(512), args, 0, stream);
}

// Round 5
// 1516.453 us; speedup vs baseline: 3.8347x; 1.0009x over previous
//
#include <hip/hip_runtime.h>
#include <stdint.h>

// SEQ=256, B=64, DIM=1024, UNITS=1024, 4U=4096
typedef unsigned short ushort_t;
typedef __attribute__((ext_vector_type(8))) short s16x8;
typedef __attribute__((ext_vector_type(4))) float f32x4;
typedef __attribute__((ext_vector_type(4))) unsigned short u16x4;

#define TO_GLB(p) ((const __attribute__((address_space(1))) void*)(p))
#define TO_LDS(p) ((__attribute__((address_space(3))) void*)(p))

__device__ __forceinline__ ushort_t f2bf(float f) {
  union { float f; uint32_t u; } v; v.f = f;
  uint32_t u = v.u;
  uint32_t r = (u + 0x7FFFu + ((u >> 16) & 1u)) >> 16;
  return (ushort_t)r;
}
__device__ __forceinline__ float bf2f(ushort_t b) {
  union { uint32_t u; float f; } v; v.u = ((uint32_t)b) << 16;
  return v.f;
}
__device__ __forceinline__ float sigm(float x) {
  x = fminf(fmaxf(x, -30.f), 30.f);
  return 1.0f / (1.0f + __expf(-x));
}
__device__ __forceinline__ float tanh_f(float x) {
  x = fminf(fmaxf(x, -15.f), 15.f);
  float t = __expf(2.0f * x);
  return (t - 1.0f) / (t + 1.0f);
}

// ---------------- convert f32 -> bf16, 4 elems/thread ----------------
__global__ void conv_f32_to_bf16(const float* __restrict__ src,
                                 ushort_t* __restrict__ dst, int n4) {
  int i = blockIdx.x * blockDim.x + threadIdx.x;
  if (i < n4) {
    float4 v = ((const float4*)src)[i];
    u16x4 o;
    o[0] = f2bf(v.x); o[1] = f2bf(v.y); o[2] = f2bf(v.z); o[3] = f2bf(v.w);
    *(u16x4*)(dst + 4 * (size_t)i) = o;
  }
}

// ---------------- init h0 (bf16) from hx ----------------
__global__ void init_h(const float* __restrict__ hx, ushort_t* __restrict__ h0, int n) {
  int i = blockIdx.x * blockDim.x + threadIdx.x;
  if (i < n) h0[i] = f2bf(hx[i]);
}

// ---------------- x_proj GEMM: C[16384][4096] = A @ W_ih^T + b_ih + b_hh ----
__global__ __launch_bounds__(256) void gemm_xproj(
    const ushort_t* __restrict__ A,   // x bf16 [16384][1024]
    const ushort_t* __restrict__ Bw,  // W_ih bf16 [4096][1024]
    const float* __restrict__ b_ih, const float* __restrict__ b_hh,
    ushort_t* __restrict__ C)         // x_proj bf16 [16384][4096]
{
  __shared__ ushort_t As[128 * 32];
  __shared__ ushort_t Bs[128 * 32];
  const int t = threadIdx.x;
  const int lane = t & 63;
  const int wid = t >> 6;
  const int wr = wid >> 1, wc = wid & 1;
  const size_t tm = (size_t)blockIdx.x * 128;
  const size_t tn = (size_t)blockIdx.y * 128;

  f32x4 acc[4][4];
  const f32x4 zero = {0.f, 0.f, 0.f, 0.f};
#pragma unroll
  for (int m = 0; m < 4; m++)
#pragma unroll
    for (int n = 0; n < 4; n++) acc[m][n] = zero;

  for (int k0 = 0; k0 < 1024; k0 += 32) {
    __syncthreads();
#pragma unroll
    for (int i = 0; i < 2; i++) {
      int row = i * 64 + (t >> 2);
      int kc = (t & 3) * 8;
      const ushort_t* ga = A + (tm + row) * 1024 + k0 + kc;
      __builtin_amdgcn_global_load_lds(TO_GLB(ga),
          TO_LDS((char*)As + (i * 256 + wid * 64) * 16), 16, 0, 0);
      const ushort_t* gb = Bw + (tn + row) * 1024 + k0 + kc;
      __builtin_amdgcn_global_load_lds(TO_GLB(gb),
          TO_LDS((char*)Bs + (i * 256 + wid * 64) * 16), 16, 0, 0);
    }
    __syncthreads();
    s16x8 af[4], bfr[4];
#pragma unroll
    for (int m = 0; m < 4; m++) {
      int r = wr * 64 + m * 16 + (lane & 15);
      af[m] = *(const s16x8*)((const char*)As + r * 64 + (lane >> 4) * 16);
    }
#pragma unroll
    for (int n = 0; n < 4; n++) {
      int r = wc * 64 + n * 16 + (lane & 15);
      bfr[n] = *(const s16x8*)((const char*)Bs + r * 64 + (lane >> 4) * 16);
    }
#pragma unroll
    for (int m = 0; m < 4; m++)
#pragma unroll
      for (int n = 0; n < 4; n++)
        acc[m][n] = __builtin_amdgcn_mfma_f32_16x16x32_bf16(af[m], bfr[n], acc[m][n], 0, 0, 0);
  }

#pragma unroll
  for (int m = 0; m < 4; m++)
#pragma unroll
    for (int n = 0; n < 4; n++)
#pragma unroll
      for (int j = 0; j < 4; j++) {
        size_t row = tm + wr * 64 + m * 16 + ((lane >> 4) << 2) + j;
        int col = (int)tn + wc * 64 + n * 16 + (lane & 15);
        float v = acc[m][n][j] + b_ih[col] + b_hh[col];
        C[row * 4096 + col] = f2bf(v);
      }
}

// ---------------- persistent LSTM scan, data-flow sync (fence-free) -------
// 128 blocks = 4 batch-groups x 32 unit-groups; 512 threads (8 waves).
// W_hh fragments pinned in VGPRs via asm keep-alive (compiler must not
// rematerialize the loads into the step loop). Cross-block h/flags via sc1
// accesses meeting at the LLC; no acquire fence, no release writeback.
// Output stores are issued AFTER the flag (off the critical path).
__global__ __launch_bounds__(512, 2) void lstm_scan(
    const ushort_t* __restrict__ whhb,   // W_hh bf16 [4096][1024]
    const ushort_t* __restrict__ xproj,  // bf16 [16384][4096]
    const float* __restrict__ reset,     // f32 [256*64]
    const float* __restrict__ cx,        // f32 [64*1024]
    ushort_t* __restrict__ h0buf, ushort_t* __restrict__ h1buf,
    unsigned int* __restrict__ flags,    // [128], zeroed before launch
    float* __restrict__ out_h0, float* __restrict__ out_h1,
    float* __restrict__ out_cs)
{
  __shared__ char smem[40960];
  char* hs = smem;                        // h tile [16][2048B], XOR-swizzled
  float* gsh = (float*)(smem + 32768);    // gates [16][128], col-swizzled

  const int t = threadIdx.x;
  const int lane = t & 63;
  const int w = t >> 6;
  const int j16 = lane & 15;
  const int q = lane >> 4;
  const int blk = blockIdx.x;
  const int bg = blk >> 5;       // batch group 0..3
  const int ug = blk & 31;       // unit group 0..31
  const int b0 = bg * 16;
  const int u0 = ug * 32;

  // ---- permanent weight fragments: wave w owns gate-rows lr = w*16..+16 ----
  s16x8 bfrag[32];
  {
    int lr = w * 16 + j16;
    int g = lr >> 5, lu = lr & 31;
    const ushort_t* wrow = whhb + ((size_t)(g * 1024 + u0 + lu)) * 1024 + q * 8;
#pragma unroll
    for (int kk = 0; kk < 32; kk++)
      bfrag[kk] = *(const s16x8*)(wrow + kk * 32);
  }
  // Pin fragments in VGPRs: false def -> compiler cannot rematerialize the
  // global loads inside the step loop (round-4 bug: VGPR_Count=116 < 128
  // needed => weights were re-streamed from L2 every step).
#pragma unroll
  for (int kk = 0; kk < 32; kk++)
    asm volatile("" : "+v"(bfrag[kk]));

  // ---- persistent cell state: thread owns (b_local, lu_t) ----
  const int b_local = t >> 5;    // 0..15
  const int lu_t = t & 31;       // 0..31
  float c_reg = cx[(size_t)(b0 + b_local) * 1024 + u0 + lu_t];

  // staging coords: thread loads row sr, 64B chunk sc
  const int sr = t & 15;
  const int sc = t >> 4;

  for (int s = 0; s < 256; s++) {
    const ushort_t* hc = (s & 1) ? h1buf : h0buf;
    ushort_t* hn = (s & 1) ? h0buf : h1buf;

    // prefetch xproj/reset for this step (independent of h -> hides under poll)
    const size_t xb = ((size_t)s * 64 + b0 + b_local) * 4096 + u0 + lu_t;
    ushort_t xp0 = xproj[xb];
    ushort_t xp1 = xproj[xb + 1024];
    ushort_t xp2 = xproj[xb + 2048];
    ushort_t xp3 = xproj[xb + 3072];
    float m2 = 1.0f - reset[s * 64 + b0 + b_local];
    float mrow = reset[s * 64 + b0 + sr];

    // ---- wait for the 32 producers of our batch-group (skip at s=0) ----
    if (s > 0) {
      if (w == 0 && lane < 32) {
        const unsigned int* fp = flags + bg * 32 + lane;
        while (__hip_atomic_load(fp, __ATOMIC_RELAXED, __HIP_MEMORY_SCOPE_AGENT)
               < (unsigned int)s) {}
      }
      __syncthreads();   // also a compiler barrier: h loads stay below the poll
    }

    // ---- stage h[16][1024] -> LDS (sc1 8B loads meet producer at the LLC) ----
    {
      const char* src = (const char*)(hc + (size_t)(b0 + sr) * 1024 + sc * 32);
#pragma unroll
      for (int jj = 0; jj < 8; jj++) {
        unsigned long long v = __hip_atomic_load(
            (const unsigned long long*)(src + jj * 8),
            __ATOMIC_RELAXED, __HIP_MEMORY_SCOPE_AGENT);
        if (mrow != 0.0f) v = 0ull;   // episode reset: h := 0
        int off = (sr * 2048 + sc * 64 + jj * 8) ^ ((sr & 7) << 4);
        *(unsigned long long*)(hs + off) = v;
      }
    }
    __syncthreads();

    // ---- full-K MFMA: wave computes gates[16 batch][16 gate-rows] ----
    f32x4 acc0 = {0.f, 0.f, 0.f, 0.f}, acc1 = {0.f, 0.f, 0.f, 0.f};
#pragma unroll
    for (int kk = 0; kk < 32; kk += 2) {
      int off0 = (j16 * 2048 + kk * 64 + q * 16) ^ ((j16 & 7) << 4);
      int off1 = (j16 * 2048 + (kk + 1) * 64 + q * 16) ^ ((j16 & 7) << 4);
      s16x8 a0 = *(const s16x8*)(hs + off0);
      s16x8 a1 = *(const s16x8*)(hs + off1);
      acc0 = __builtin_amdgcn_mfma_f32_16x16x32_bf16(a0, bfrag[kk], acc0, 0, 0, 0);
      acc1 = __builtin_amdgcn_mfma_f32_16x16x32_bf16(a1, bfrag[kk + 1], acc1, 0, 0, 0);
    }

    // ---- stash gates: gsh[row][col ^ ((row&7)<<2)], row=batch, col=gate-row ----
#pragma unroll
    for (int jj = 0; jj < 4; jj++) {
      int row = q * 4 + jj;
      int col = (w * 16 + j16) ^ ((row & 7) << 2);
      gsh[row * 128 + col] = acc0[jj] + acc1[jj];
    }
    __syncthreads();

    // ---- cell update ----
    float gv0 = gsh[b_local * 128 + ((0 * 32 + lu_t) ^ ((b_local & 7) << 2))] + bf2f(xp0);
    float gv1 = gsh[b_local * 128 + ((1 * 32 + lu_t) ^ ((b_local & 7) << 2))] + bf2f(xp1);
    float gv2 = gsh[b_local * 128 + ((2 * 32 + lu_t) ^ ((b_local & 7) << 2))] + bf2f(xp2);
    float gv3 = gsh[b_local * 128 + ((3 * 32 + lu_t) ^ ((b_local & 7) << 2))] + bf2f(xp3);
    float ii = sigm(gv0), ff = sigm(gv1), G = tanh_f(gv2), oo = sigm(gv3);
    float cn = ff * (c_reg * m2) + ii * G;
    float hv = oo * tanh_f(cn);
    c_reg = cn;

    // ---- h store FIRST: pack lane-pairs to one 4B agent-scope (sc1) store ----
    {
      unsigned int mybits = (unsigned int)f2bf(hv);
      unsigned int pb = (unsigned int)__shfl_xor((int)mybits, 1, 64);
      if ((t & 1) == 0) {
        unsigned int pack = mybits | (pb << 16);
        __hip_atomic_store(
            (unsigned int*)(hn + (size_t)(b0 + b_local) * 1024 + u0 + lu_t),
            pack, __ATOMIC_RELAXED, __HIP_MEMORY_SCOPE_AGENT);
      }
    }

    // drain h stores, join all waves, release flag
    asm volatile("s_waitcnt vmcnt(0)" ::: "memory");
    __syncthreads();
    if (t == 0)
      __hip_atomic_store(&flags[blk], (unsigned int)(s + 1),
                         __ATOMIC_RELAXED, __HIP_MEMORY_SCOPE_AGENT);

    // ---- output stores AFTER the flag: off the critical path ----
    size_t ob = ((size_t)s * 64 + b0 + b_local) * 1024 + u0 + lu_t;
    out_cs[ob] = cn;
    out_h0[ob] = hv;
    out_h1[ob] = hv;
  }
}

extern "C" void kernel_launch(void* const* d_in, const int* in_sizes, int n_in,
                              void* d_out, int out_size, void* d_ws, size_t ws_size,
                              hipStream_t stream) {
  const float* x     = (const float*)d_in[0];
  const float* hx    = (const float*)d_in[1];
  const float* cx    = (const float*)d_in[2];
  const float* reset = (const float*)d_in[3];
  const float* W_ih  = (const float*)d_in[4];
  const float* W_hh  = (const float*)d_in[5];
  const float* b_ih  = (const float*)d_in[6];
  const float* b_hh  = (const float*)d_in[7];
  float* out = (float*)d_out;

  char* ws = (char*)d_ws;
  ushort_t* xbf   = (ushort_t*)(ws);                  // 33,554,432 B
  ushort_t* wihb  = (ushort_t*)(ws + 33554432);       //  8,388,608 B
  ushort_t* whhb  = (ushort_t*)(ws + 41943040);       //  8,388,608 B
  ushort_t* xproj = (ushort_t*)(ws + 50331648);       // 134,217,728 B
  ushort_t* h0    = (ushort_t*)(ws + 184549376);      // 131,072 B
  ushort_t* h1    = (ushort_t*)(ws + 184680448);      // 131,072 B
  unsigned int* flags = (unsigned int*)(ws + 184811520);  // 512 B

  hipMemsetAsync(flags, 0, 128 * sizeof(unsigned int), stream);
  hipLaunchKernelGGL(conv_f32_to_bf16, dim3(16384), dim3(256), 0, stream, x, xbf, 4194304);
  hipLaunchKernelGGL(conv_f32_to_bf16, dim3(4096), dim3(256), 0, stream, W_ih, wihb, 1048576);
  hipLaunchKernelGGL(conv_f32_to_bf16, dim3(4096), dim3(256), 0, stream, W_hh, whhb, 1048576);
  hipLaunchKernelGGL(init_h, dim3(256), dim3(256), 0, stream, hx, h0, 65536);
  hipLaunchKernelGGL(gemm_xproj, dim3(128, 32), dim3(256), 0, stream, xbf, wihb, b_ih, b_hh, xproj);

  float* oh0 = out;
  float* oh1 = out + 16777216;
  float* ocs = out + 33554432;

  const ushort_t* whhb_c = whhb;
  const ushort_t* xproj_c = xproj;
  void* args[] = {(void*)&whhb_c, (void*)&xproj_c, (void*)&reset, (void*)&cx,
                  (void*)&h0, (void*)&h1, (void*)&flags,
                  (void*)&oh0, (void*)&oh1, (void*)&ocs};
  hipLaunchCooperativeKernel((void*)lstm_scan, dim3(128), dim3(512), args, 0, stream);
}